// Round 2
// baseline (530.483 us; speedup 1.0000x reference)
//
#include <hip/hip_runtime.h>
#include <math.h>

// DiffGatedTopK: x (16384 x 4096 fp32). Per row: k=614 top-k mask, gain =
// sigmoid(top1-top2)*3+1, out = x*mask*gain.
//
// One WAVE per row, row resident in registers (64 vals/lane). Exact k-th
// largest bit pattern via 32-step bisection over the order-preserving uint
// space, counting with ballot+popc (scalar pipe) — no LDS, no atomics, no
// barriers. Ties at the boundary (exact duplicate bit patterns) resolved
// lowest-index-first via ballot ranks, matching jax.lax.top_k.

#define D     4096
#define K     614            // int(4096 * 0.15)
#define BLOCK 256
#define VPT   64             // values per lane
#define NB    16             // float4 batches per lane

__device__ __forceinline__ unsigned int f2ord(float f) {
    unsigned int b = __float_as_uint(f);
    return (b & 0x80000000u) ? ~b : (b | 0x80000000u);
}
__device__ __forceinline__ float ord2f(unsigned int u) {
    unsigned int b = (u & 0x80000000u) ? (u ^ 0x80000000u) : ~u;
    return __uint_as_float(b);
}

__global__ __launch_bounds__(BLOCK, 5)
void diffgated_topk(const float* __restrict__ x, float* __restrict__ out, int rows) {
    const int lane = threadIdx.x & 63;
    const int wav  = threadIdx.x >> 6;
    const int row  = blockIdx.x * 4 + wav;
    if (row >= rows) return;                      // wave-uniform
    const float* xrow = x + (size_t)row * D;
    float*       orow = out + (size_t)row * D;

    // ---- load row into registers (ordered uints), track per-lane top-2 ----
    unsigned int u[VPT];
    float m1 = -INFINITY, m2 = -INFINITY;
    #pragma unroll
    for (int b = 0; b < NB; ++b) {
        float4 v = ((const float4*)xrow)[b * 64 + lane];
        float vs[4] = { v.x, v.y, v.z, v.w };
        #pragma unroll
        for (int j = 0; j < 4; ++j) {
            float f = vs[j];
            if (f > m1) { m2 = m1; m1 = f; } else if (f > m2) { m2 = f; }
            u[b * 4 + j] = f2ord(f);
        }
    }

    // ---- wave top-2 butterfly reduce ----
    #pragma unroll
    for (int off = 32; off; off >>= 1) {
        float o1 = __shfl_xor(m1, off);
        float o2 = __shfl_xor(m2, off);
        float hi = fmaxf(m1, o1), lo2 = fminf(m1, o1);
        m2 = fmaxf(lo2, fmaxf(m2, o2));
        m1 = hi;
    }
    const float gain = 1.0f / (1.0f + expf(-(m1 - m2))) * 3.0f + 1.0f;

    // ---- 32-step bisection for exact k-th-largest bit pattern ----
    // invariant: count(u >= lo) >= K, count(u >= hi) < K  (hi as 2^32 works:
    // count(>= 2^32) = 0). Terminates with hi = lo+1 => lo == v_k exactly.
    unsigned long long lo = 0ull, hi = 0x100000000ull;
    for (int it = 0; it < 32; ++it) {
        unsigned int mid = (unsigned int)((lo + hi) >> 1);
        int cnt = 0;
        #pragma unroll
        for (int j = 0; j < VPT; ++j)
            cnt += (int)__popcll(__ballot(u[j] >= mid));
        if (cnt >= K) lo = mid; else hi = mid;
    }
    const unsigned int ut = (unsigned int)lo;     // exact k-th largest pattern

    // ---- boundary bookkeeping ----
    int cnt_gt = 0, cnt_eq = 0;
    #pragma unroll
    for (int j = 0; j < VPT; ++j) {
        cnt_gt += (int)__popcll(__ballot(u[j] >  ut));
        cnt_eq += (int)__popcll(__ballot(u[j] == ut));
    }
    const int needed = K - cnt_gt;                // #equals to include (>=1)

    // ---- output ----
    if (cnt_eq == needed) {
        // common case: every element equal to the threshold is included
        #pragma unroll
        for (int b = 0; b < NB; ++b) {
            float4 o; float* op = (float*)&o;
            #pragma unroll
            for (int j = 0; j < 4; ++j) {
                unsigned int uu = u[b * 4 + j];
                op[j] = (uu >= ut) ? ord2f(uu) * gain : 0.0f;
            }
            ((float4*)orow)[b * 64 + lane] = o;
        }
    } else {
        // rare: exact-duplicate patterns straddle rank K -> lowest index first.
        // element global index = 256*b + 4*lane + j (b-major, lane, then j).
        const unsigned long long ltmask =
            (lane == 0) ? 0ull : ((~0ull) >> (64 - lane));
        int eq_before = 0;                        // equals in earlier batches
        #pragma unroll
        for (int b = 0; b < NB; ++b) {
            unsigned long long bal[4];
            #pragma unroll
            for (int j = 0; j < 4; ++j) bal[j] = __ballot(u[b * 4 + j] == ut);
            float4 o; float* op = (float*)&o;
            #pragma unroll
            for (int j = 0; j < 4; ++j) {
                unsigned int uu = u[b * 4 + j];
                float f = 0.0f;
                if (uu > ut) {
                    f = ord2f(uu) * gain;
                } else if (uu == ut) {
                    int r = eq_before;
                    #pragma unroll
                    for (int j2 = 0; j2 < 4; ++j2) {
                        r += (int)__popcll(bal[j2] & ltmask);      // lanes < me
                        if (j2 < j) r += (int)((bal[j2] >> lane) & 1ull);
                    }
                    if (r < needed) f = ord2f(uu) * gain;
                }
                op[j] = f;
            }
            ((float4*)orow)[b * 64 + lane] = o;
            #pragma unroll
            for (int j2 = 0; j2 < 4; ++j2)
                eq_before += (int)__popcll(bal[j2]);
        }
    }
}

extern "C" void kernel_launch(void* const* d_in, const int* in_sizes, int n_in,
                              void* d_out, int out_size, void* d_ws, size_t ws_size,
                              hipStream_t stream) {
    const float* x = (const float*)d_in[0];
    float* out = (float*)d_out;
    const int rows = in_sizes[0] / D;             // 16384
    diffgated_topk<<<dim3((rows + 3) / 4), dim3(BLOCK), 0, stream>>>(x, out, rows);
}

// Round 3
// 471.664 us; speedup vs baseline: 1.1247x; 1.1247x over previous
//
#include <hip/hip_runtime.h>
#include <math.h>

// DiffGatedTopK: x (16384 x 4096 fp32). Per row: k=614 top-k mask, gain =
// sigmoid(top1-top2)*3+1, out = x*mask*gain.
//
// One WAVE per row, row resident in registers as order-preserving uints
// (64/lane). Exact k-th-largest bit pattern via bisection with ballot+popc
// counting, EARLY-EXITING as soon as count(u >= lo) == K (always happens for
// distinct values, ~12-15 iters); exact-duplicate boundary ties fall to a
// rare ballot-rank path (lowest index first, matching jax.lax.top_k).
// No LDS, no atomics, no barriers. NT stores keep the L3-resident input hot.

#define D     4096
#define K     614            // int(4096 * 0.15)
#define BLOCK 256
#define VPT   64             // values per lane
#define NB    16             // float4 batches per lane

typedef float f32x4 __attribute__((ext_vector_type(4)));

__device__ __forceinline__ unsigned int f2ord(float f) {
    unsigned int b = __float_as_uint(f);
    return ((int)b >= 0) ? (b | 0x80000000u) : ~b;
}
__device__ __forceinline__ float ord2f(unsigned int u) {
    return __uint_as_float(((int)u < 0) ? (u ^ 0x80000000u) : ~u);
}

__global__ __launch_bounds__(BLOCK, 4)   // 128-VGPR cap: u[64]+temps fits, no spill
void diffgated_topk(const float* __restrict__ x, float* __restrict__ out, int rows) {
    const int lane = threadIdx.x & 63;
    const int wav  = threadIdx.x >> 6;
    const int row  = blockIdx.x * 4 + wav;
    if (row >= rows) return;                          // wave-uniform
    const f32x4* xrow = (const f32x4*)(x + (size_t)row * D);
    f32x4*       orow = (f32x4*)(out + (size_t)row * D);

    // ---- load row -> registers (ordered uints), per-lane top-2 in uint domain ----
    unsigned int u[VPT];
    unsigned int m1 = 0u, m2 = 0u;                    // ordered 0 == -inf
    #pragma unroll
    for (int b = 0; b < NB; ++b) {
        f32x4 v = xrow[b * 64 + lane];
        #pragma unroll
        for (int j = 0; j < 4; ++j) {
            unsigned int q = f2ord(v[j]);
            unsigned int lo2 = min(m1, q);
            m1 = max(m1, q);
            m2 = max(m2, lo2);
            u[b * 4 + j] = q;
        }
    }

    // ---- wave top-2 butterfly ----
    #pragma unroll
    for (int off = 32; off; off >>= 1) {
        unsigned int o1 = __shfl_xor(m1, off);
        unsigned int o2 = __shfl_xor(m2, off);
        unsigned int hi2 = max(m1, o1), lo2 = min(m1, o1);
        m2 = max(m2, max(lo2, o2));
        m1 = hi2;
    }
    const float gain = 3.0f / (1.0f + expf(-(ord2f(m1) - ord2f(m2)))) + 1.0f;

    // ---- bisection for exact k-th-largest pattern, early exit on cnt==K ----
    // invariant: count(>= lo) >= K > count(>= hi)
    unsigned long long lo = 0ull, hi = 0x100000000ull;
    int cnt_lo = D, cnt_hi = 0;
    while (hi - lo > 1ull) {
        unsigned int mid = (unsigned int)((lo + hi) >> 1);
        int cnt = 0;
        #pragma unroll
        for (int j = 0; j < VPT; ++j)
            cnt += (int)__popcll(__ballot(u[j] >= mid));
        if (cnt >= K) { lo = mid; cnt_lo = cnt; if (cnt == K) break; }
        else          { hi = mid; cnt_hi = cnt; }
    }
    const unsigned int ut = (unsigned int)lo;         // exact k-th largest pattern
    const float g = gain;

    // ---- output ----
    if (cnt_lo == K) {
        // exact-count fast path: keep iff u >= ut (no boundary ties to split)
        #pragma unroll
        for (int b = 0; b < NB; ++b) {
            f32x4 o;
            #pragma unroll
            for (int j = 0; j < 4; ++j) {
                unsigned int uu = u[b * 4 + j];
                o[j] = (uu >= ut) ? ord2f(uu) * g : 0.0f;
            }
            __builtin_nontemporal_store(o, orow + b * 64 + lane);
        }
    } else {
        // rare: exact-duplicate patterns straddle rank K -> lowest index first.
        // element global index = 256*b + 4*lane + j.
        const int needed = K - cnt_hi;                // #equals to include (>=1)
        const unsigned long long ltmask =
            (lane == 0) ? 0ull : ((~0ull) >> (64 - lane));
        int eq_before = 0;                            // equals in earlier batches
        #pragma unroll
        for (int b = 0; b < NB; ++b) {
            unsigned long long bal[4];
            #pragma unroll
            for (int j = 0; j < 4; ++j) bal[j] = __ballot(u[b * 4 + j] == ut);
            f32x4 o;
            #pragma unroll
            for (int j = 0; j < 4; ++j) {
                unsigned int uu = u[b * 4 + j];
                float f = 0.0f;
                if (uu > ut) {
                    f = ord2f(uu) * g;
                } else if (uu == ut) {
                    int r = eq_before;
                    #pragma unroll
                    for (int j2 = 0; j2 < 4; ++j2) {
                        r += (int)__popcll(bal[j2] & ltmask);     // lanes < me
                        if (j2 < j) r += (int)((bal[j2] >> lane) & 1ull);
                    }
                    if (r < needed) f = ord2f(uu) * g;
                }
                o[j] = f;
            }
            __builtin_nontemporal_store(o, orow + b * 64 + lane);
            #pragma unroll
            for (int j2 = 0; j2 < 4; ++j2)
                eq_before += (int)__popcll(bal[j2]);
        }
    }
}

extern "C" void kernel_launch(void* const* d_in, const int* in_sizes, int n_in,
                              void* d_out, int out_size, void* d_ws, size_t ws_size,
                              hipStream_t stream) {
    const float* x = (const float*)d_in[0];
    float* out = (float*)d_out;
    const int rows = in_sizes[0] / D;                 // 16384
    diffgated_topk<<<dim3((rows + 3) / 4), dim3(BLOCK), 0, stream>>>(x, out, rows);
}